// Round 9
// baseline (86.397 us; speedup 1.0000x reference)
//
#include <hip/hip_runtime.h>

// Problem constants (from reference setup_inputs): B=8, L=4096, D=256, f32.
#define BATCH 8
#define SEQ   4096
#define DIM   256

// Native clang vector type — required by __builtin_nontemporal_store.
typedef float floatx4 __attribute__((ext_vector_type(4)));

// R8 lesson: warm k1 (inputs L3-resident) is as slow as cold -> not a memory
// wall; k3 proves the memory system has 5x headroom. R2's k1 form (float4,
// 4 cols/lane, 1 wave/tile, plain unroll, no min-waves bound) was plausibly
// ~27us (never in R2's top-5, k1+k3 ~ 55us combined) and every later round
// replaced it with batching/dbuf machinery that pinned k1 at ~48us.
// This round: faithful revert to the R2 shape for k1 and k3; keep R8's
// wave-parallel k2. One variable vs R4-R8.

// ---------------------------------------------------------------------------
// Kernel 1: per-(b, tile) aggregate. One wave per tile; 4 cols/lane (float4).
// Two independent chains: running product of a (pr,pi) and plain recurrence
// from zero (yr,yi). agg slot = (pr,pi,yr,yi) per column.
// ---------------------------------------------------------------------------
template <int NT, int T>
__global__ __launch_bounds__(256) void k_tile_agg(
    const float* __restrict__ Ar, const float* __restrict__ Ai,
    const float* __restrict__ Xr, const float* __restrict__ Xi,
    float4* __restrict__ agg)
{
    int wave = threadIdx.x >> 6;
    int lane = threadIdx.x & 63;
    int tile = blockIdx.x * 4 + wave;        // in [0, BATCH*NT)
    int b = tile / NT;
    int j = tile - b * NT;
    int d = lane * 4;

    size_t base = ((size_t)b * SEQ + (size_t)j * T) * DIM + d;

    float pr[4], pi[4], yr[4], yi[4];
#pragma unroll
    for (int k = 0; k < 4; ++k) { pr[k] = 1.f; pi[k] = 0.f; yr[k] = 0.f; yi[k] = 0.f; }

#pragma unroll 4
    for (int t = 0; t < T; ++t) {
        size_t idx = base + (size_t)t * DIM;
        float4 a_re = *(const float4*)(Ar + idx);
        float4 a_im = *(const float4*)(Ai + idx);
        float4 x_re = *(const float4*)(Xr + idx);
        float4 x_im = *(const float4*)(Xi + idx);
        const float* par = (const float*)&a_re;
        const float* pai = (const float*)&a_im;
        const float* pxr = (const float*)&x_re;
        const float* pxi = (const float*)&x_im;
#pragma unroll
        for (int k = 0; k < 4; ++k) {
            float a_r = par[k], a_i = pai[k];
            float npr = a_r * pr[k] - a_i * pi[k];
            float npi = a_r * pi[k] + a_i * pr[k];
            pr[k] = npr; pi[k] = npi;
            float nyr = a_r * yr[k] - a_i * yi[k] + pxr[k];
            float nyi = a_r * yi[k] + a_i * yr[k] + pxi[k];
            yr[k] = nyr; yi[k] = nyi;
        }
    }

    size_t o = ((size_t)b * NT + j) * DIM + d;
#pragma unroll
    for (int k = 0; k < 4; ++k)
        agg[o + k] = make_float4(pr[k], pi[k], yr[k], yi[k]);
}

// ---------------------------------------------------------------------------
// Kernel 2: wave-parallel exclusive scan of tile aggregates along j.
// One wave per (b,d) column; lane owns NTPL = NT/64 consecutive tiles.
// ---------------------------------------------------------------------------
template <int NT>
__global__ __launch_bounds__(256) void k_scan_agg(float4* __restrict__ agg)
{
    constexpr int NTPL = NT / 64;
    int lane = threadIdx.x & 63;
    int col  = blockIdx.x * 4 + (threadIdx.x >> 6);   // in [0, BATCH*DIM)
    int b = col >> 8;          // / DIM
    int d = col & 255;         // % DIM

    float4 v[NTPL];
    float lar = 1.f, lai = 0.f, lxr = 0.f, lxi = 0.f;
#pragma unroll
    for (int m = 0; m < NTPL; ++m) {
        v[m] = agg[((size_t)b * NT + lane * NTPL + m) * DIM + d];
        float nar = v[m].x * lar - v[m].y * lai;
        float nai = v[m].x * lai + v[m].y * lar;
        float nxr = v[m].x * lxr - v[m].y * lxi + v[m].z;
        float nxi = v[m].x * lxi + v[m].y * lxr + v[m].w;
        lar = nar; lai = nai; lxr = nxr; lxi = nxi;
    }

    float ar = lar, ai = lai, xr = lxr, xi = lxi;
#pragma unroll
    for (int off = 1; off < 64; off <<= 1) {
        float par = __shfl_up(ar, (unsigned)off, 64);
        float pai = __shfl_up(ai, (unsigned)off, 64);
        float pxr = __shfl_up(xr, (unsigned)off, 64);
        float pxi = __shfl_up(xi, (unsigned)off, 64);
        if (lane >= off) {
            float nar = ar * par - ai * pai;
            float nai = ar * pai + ai * par;
            float nxr = ar * pxr - ai * pxi + xr;
            float nxi = ar * pxi + ai * pxr + xi;
            ar = nar; ai = nai; xr = nxr; xi = nxi;
        }
    }

    float ear = __shfl_up(ar, 1u, 64);
    float eai = __shfl_up(ai, 1u, 64);
    float exr = __shfl_up(xr, 1u, 64);
    float exi = __shfl_up(xi, 1u, 64);
    if (lane == 0) { ear = 1.f; eai = 0.f; exr = 0.f; exi = 0.f; }

#pragma unroll
    for (int m = 0; m < NTPL; ++m) {
        agg[((size_t)b * NT + lane * NTPL + m) * DIM + d] =
            make_float4(exr, exi, 0.f, 0.f);
        float nar = v[m].x * ear - v[m].y * eai;
        float nai = v[m].x * eai + v[m].y * ear;
        float nxr = v[m].x * exr - v[m].y * exi + v[m].z;
        float nxi = v[m].x * exi + v[m].y * exr + v[m].w;
        ear = nar; eai = nai; exr = nxr; exi = nxi;
    }
}

// ---------------------------------------------------------------------------
// Kernel 3: seed y from tile prefix, recompute recurrence, write out.
// One wave per tile; 4 cols/lane (float4); two contiguous float4 nt-stores
// per lane per t ([B,L,D,2] layout).
// ---------------------------------------------------------------------------
template <int NT, int T>
__global__ __launch_bounds__(256) void k_apply(
    const float* __restrict__ Ar, const float* __restrict__ Ai,
    const float* __restrict__ Xr, const float* __restrict__ Xi,
    const float4* __restrict__ agg, float* __restrict__ outf)
{
    int wave = threadIdx.x >> 6;
    int lane = threadIdx.x & 63;
    int tile = blockIdx.x * 4 + wave;
    int b = tile / NT;
    int j = tile - b * NT;
    int d = lane * 4;

    float yr[4], yi[4];
    size_t o = ((size_t)b * NT + j) * DIM + d;
#pragma unroll
    for (int k = 0; k < 4; ++k) {
        float4 p = agg[o + k];
        yr[k] = p.x; yi[k] = p.y;
    }

    size_t base = ((size_t)b * SEQ + (size_t)j * T) * DIM + d;
#pragma unroll 4
    for (int t = 0; t < T; ++t) {
        size_t idx = base + (size_t)t * DIM;
        float4 a_re = *(const float4*)(Ar + idx);
        float4 a_im = *(const float4*)(Ai + idx);
        float4 x_re = *(const float4*)(Xr + idx);
        float4 x_im = *(const float4*)(Xi + idx);
        const float* par = (const float*)&a_re;
        const float* pai = (const float*)&a_im;
        const float* pxr = (const float*)&x_re;
        const float* pxi = (const float*)&x_im;
#pragma unroll
        for (int k = 0; k < 4; ++k) {
            float nyr = par[k] * yr[k] - pai[k] * yi[k] + pxr[k];
            float nyi = par[k] * yi[k] + pai[k] * yr[k] + pxi[k];
            yr[k] = nyr; yi[k] = nyi;
        }
        floatx4 o1 = (floatx4){yr[0], yi[0], yr[1], yi[1]};
        floatx4 o2 = (floatx4){yr[2], yi[2], yr[3], yi[3]};
        float* po = outf + 2 * idx;
        __builtin_nontemporal_store(o1, (floatx4*)(po));
        __builtin_nontemporal_store(o2, (floatx4*)(po + 4));
    }
}

extern "C" void kernel_launch(void* const* d_in, const int* in_sizes, int n_in,
                              void* d_out, int out_size, void* d_ws, size_t ws_size,
                              hipStream_t stream)
{
    const float* Ar = (const float*)d_in[0];
    const float* Ai = (const float*)d_in[1];
    const float* Xr = (const float*)d_in[2];
    const float* Xi = (const float*)d_in[3];
    float* outf = (float*)d_out;
    float4* agg = (float4*)d_ws;

    dim3 block(256);

    if (ws_size >= (size_t)BATCH * 256 * DIM * sizeof(float4)) {
        constexpr int NT = 256, T = SEQ / 256;   // T = 16
        dim3 grid1((BATCH * NT) / 4);            // 512 blocks, 1 wave/tile
        k_tile_agg<NT, T><<<grid1, block, 0, stream>>>(Ar, Ai, Xr, Xi, agg);
        k_scan_agg<NT><<<(BATCH * DIM) / 4, block, 0, stream>>>(agg);
        k_apply<NT, T><<<grid1, block, 0, stream>>>(Ar, Ai, Xr, Xi, agg, outf);
    } else {
        constexpr int NT = 64, T = SEQ / 64;     // T = 64
        dim3 grid1((BATCH * NT) / 4);
        k_tile_agg<NT, T><<<grid1, block, 0, stream>>>(Ar, Ai, Xr, Xi, agg);
        k_scan_agg<NT><<<(BATCH * DIM) / 4, block, 0, stream>>>(agg);
        k_apply<NT, T><<<grid1, block, 0, stream>>>(Ar, Ai, Xr, Xi, agg, outf);
    }
}

// Round 10
// 67.899 us; speedup vs baseline: 1.2724x; 1.2724x over previous
//
#include <hip/hip_runtime.h>

// Problem constants (from reference setup_inputs): B=8, L=4096, D=256, f32.
#define BATCH 8
#define SEQ   4096
#define DIM   256

// Native clang vector type — required by __builtin_nontemporal_store.
typedef float floatx4 __attribute__((ext_vector_type(4)));

// R9 lesson: the two streaming kernels prefer DIFFERENT shapes.
//  - k1 fast form (R9, ~31us): float4, 4 cols/lane, 1 wave/tile,
//    plain __launch_bounds__(256), simple unroll-4 loop.
//  - k3 fast form (R8, ~13us): float2, 2 cols/lane, 2 waves/tile,
//    __launch_bounds__(256,8), single 16B nt-store per lane per t.
// This round combines the two measured-fast instances verbatim.

// ---------------------------------------------------------------------------
// Kernel 1: per-(b, tile) aggregate. One wave per tile; 4 cols/lane (float4).
// Two independent chains: running product of a (pr,pi) and plain recurrence
// from zero (yr,yi). agg slot = (pr,pi,yr,yi) per column.
// ---------------------------------------------------------------------------
template <int NT, int T>
__global__ __launch_bounds__(256) void k_tile_agg(
    const float* __restrict__ Ar, const float* __restrict__ Ai,
    const float* __restrict__ Xr, const float* __restrict__ Xi,
    float4* __restrict__ agg)
{
    int wave = threadIdx.x >> 6;
    int lane = threadIdx.x & 63;
    int tile = blockIdx.x * 4 + wave;        // in [0, BATCH*NT)
    int b = tile / NT;
    int j = tile - b * NT;
    int d = lane * 4;

    size_t base = ((size_t)b * SEQ + (size_t)j * T) * DIM + d;

    float pr[4], pi[4], yr[4], yi[4];
#pragma unroll
    for (int k = 0; k < 4; ++k) { pr[k] = 1.f; pi[k] = 0.f; yr[k] = 0.f; yi[k] = 0.f; }

#pragma unroll 4
    for (int t = 0; t < T; ++t) {
        size_t idx = base + (size_t)t * DIM;
        float4 a_re = *(const float4*)(Ar + idx);
        float4 a_im = *(const float4*)(Ai + idx);
        float4 x_re = *(const float4*)(Xr + idx);
        float4 x_im = *(const float4*)(Xi + idx);
        const float* par = (const float*)&a_re;
        const float* pai = (const float*)&a_im;
        const float* pxr = (const float*)&x_re;
        const float* pxi = (const float*)&x_im;
#pragma unroll
        for (int k = 0; k < 4; ++k) {
            float a_r = par[k], a_i = pai[k];
            float npr = a_r * pr[k] - a_i * pi[k];
            float npi = a_r * pi[k] + a_i * pr[k];
            pr[k] = npr; pi[k] = npi;
            float nyr = a_r * yr[k] - a_i * yi[k] + pxr[k];
            float nyi = a_r * yi[k] + a_i * yr[k] + pxi[k];
            yr[k] = nyr; yi[k] = nyi;
        }
    }

    size_t o = ((size_t)b * NT + j) * DIM + d;
#pragma unroll
    for (int k = 0; k < 4; ++k)
        agg[o + k] = make_float4(pr[k], pi[k], yr[k], yi[k]);
}

// ---------------------------------------------------------------------------
// Kernel 2: wave-parallel exclusive scan of tile aggregates along j.
// One wave per (b,d) column; lane owns NTPL = NT/64 consecutive tiles.
// ---------------------------------------------------------------------------
template <int NT>
__global__ __launch_bounds__(256) void k_scan_agg(float4* __restrict__ agg)
{
    constexpr int NTPL = NT / 64;
    int lane = threadIdx.x & 63;
    int col  = blockIdx.x * 4 + (threadIdx.x >> 6);   // in [0, BATCH*DIM)
    int b = col >> 8;          // / DIM
    int d = col & 255;         // % DIM

    float4 v[NTPL];
    float lar = 1.f, lai = 0.f, lxr = 0.f, lxi = 0.f;
#pragma unroll
    for (int m = 0; m < NTPL; ++m) {
        v[m] = agg[((size_t)b * NT + lane * NTPL + m) * DIM + d];
        float nar = v[m].x * lar - v[m].y * lai;
        float nai = v[m].x * lai + v[m].y * lar;
        float nxr = v[m].x * lxr - v[m].y * lxi + v[m].z;
        float nxi = v[m].x * lxi + v[m].y * lxr + v[m].w;
        lar = nar; lai = nai; lxr = nxr; lxi = nxi;
    }

    float ar = lar, ai = lai, xr = lxr, xi = lxi;
#pragma unroll
    for (int off = 1; off < 64; off <<= 1) {
        float par = __shfl_up(ar, (unsigned)off, 64);
        float pai = __shfl_up(ai, (unsigned)off, 64);
        float pxr = __shfl_up(xr, (unsigned)off, 64);
        float pxi = __shfl_up(xi, (unsigned)off, 64);
        if (lane >= off) {
            float nar = ar * par - ai * pai;
            float nai = ar * pai + ai * par;
            float nxr = ar * pxr - ai * pxi + xr;
            float nxi = ar * pxi + ai * pxr + xi;
            ar = nar; ai = nai; xr = nxr; xi = nxi;
        }
    }

    float ear = __shfl_up(ar, 1u, 64);
    float eai = __shfl_up(ai, 1u, 64);
    float exr = __shfl_up(xr, 1u, 64);
    float exi = __shfl_up(xi, 1u, 64);
    if (lane == 0) { ear = 1.f; eai = 0.f; exr = 0.f; exi = 0.f; }

#pragma unroll
    for (int m = 0; m < NTPL; ++m) {
        agg[((size_t)b * NT + lane * NTPL + m) * DIM + d] =
            make_float4(exr, exi, 0.f, 0.f);
        float nar = v[m].x * ear - v[m].y * eai;
        float nai = v[m].x * eai + v[m].y * ear;
        float nxr = v[m].x * exr - v[m].y * exi + v[m].z;
        float nxi = v[m].x * exi + v[m].y * exr + v[m].w;
        ear = nar; eai = nai; exr = nxr; exi = nxi;
    }
}

// ---------------------------------------------------------------------------
// Kernel 3 (R8 fast form): seed y from tile prefix, recompute recurrence,
// write out. Tile = 2 waves; 2 cols/lane (float2 loads); one contiguous
// 16B nontemporal store per lane per t ([B,L,D,2] layout).
// ---------------------------------------------------------------------------
template <int NT, int T>
__global__ __launch_bounds__(256, 8) void k_apply(
    const float* __restrict__ Ar, const float* __restrict__ Ai,
    const float* __restrict__ Xr, const float* __restrict__ Xi,
    const float4* __restrict__ agg, float* __restrict__ outf)
{
    int half = threadIdx.x >> 7;
    int wl   = threadIdx.x & 127;
    int tile = blockIdx.x * 2 + half;
    int b = tile / NT;
    int j = tile - b * NT;
    int d = wl * 2;

    float yr[2], yi[2];
    size_t o = ((size_t)b * NT + j) * DIM + d;
    {
        float4 p0 = agg[o];
        float4 p1 = agg[o + 1];
        yr[0] = p0.x; yi[0] = p0.y;
        yr[1] = p1.x; yi[1] = p1.y;
    }

    size_t base = ((size_t)b * SEQ + (size_t)j * T) * DIM + d;

#pragma unroll
    for (int t = 0; t < T; ++t) {
        size_t idx = base + (size_t)t * DIM;
        float2 a_re = *(const float2*)(Ar + idx);
        float2 a_im = *(const float2*)(Ai + idx);
        float2 x_re = *(const float2*)(Xr + idx);
        float2 x_im = *(const float2*)(Xi + idx);
        const float* par = (const float*)&a_re;
        const float* pai = (const float*)&a_im;
        const float* pxr = (const float*)&x_re;
        const float* pxi = (const float*)&x_im;
#pragma unroll
        for (int k = 0; k < 2; ++k) {
            float nyr = par[k] * yr[k] - pai[k] * yi[k] + pxr[k];
            float nyi = par[k] * yi[k] + pai[k] * yr[k] + pxi[k];
            yr[k] = nyr; yi[k] = nyi;
        }
        floatx4 o1 = (floatx4){yr[0], yi[0], yr[1], yi[1]};
        __builtin_nontemporal_store(o1, (floatx4*)(outf + 2 * idx));
    }
}

extern "C" void kernel_launch(void* const* d_in, const int* in_sizes, int n_in,
                              void* d_out, int out_size, void* d_ws, size_t ws_size,
                              hipStream_t stream)
{
    const float* Ar = (const float*)d_in[0];
    const float* Ai = (const float*)d_in[1];
    const float* Xr = (const float*)d_in[2];
    const float* Xi = (const float*)d_in[3];
    float* outf = (float*)d_out;
    float4* agg = (float4*)d_ws;

    dim3 block(256);

    if (ws_size >= (size_t)BATCH * 256 * DIM * sizeof(float4)) {
        constexpr int NT = 256, T = SEQ / 256;   // T = 16
        dim3 grid1((BATCH * NT) / 4);            // k1: 512 blocks, 1 wave/tile
        dim3 grid3((BATCH * NT) / 2);            // k3: 1024 blocks, 2 waves/tile
        k_tile_agg<NT, T><<<grid1, block, 0, stream>>>(Ar, Ai, Xr, Xi, agg);
        k_scan_agg<NT><<<(BATCH * DIM) / 4, block, 0, stream>>>(agg);
        k_apply<NT, T><<<grid3, block, 0, stream>>>(Ar, Ai, Xr, Xi, agg, outf);
    } else {
        constexpr int NT = 64, T = SEQ / 64;     // T = 64
        dim3 grid1((BATCH * NT) / 4);
        dim3 grid3((BATCH * NT) / 2);
        k_tile_agg<NT, T><<<grid1, block, 0, stream>>>(Ar, Ai, Xr, Xi, agg);
        k_scan_agg<NT><<<(BATCH * DIM) / 4, block, 0, stream>>>(agg);
        k_apply<NT, T><<<grid3, block, 0, stream>>>(Ar, Ai, Xr, Xi, agg, outf);
    }
}

// Round 11
// 66.741 us; speedup vs baseline: 1.2945x; 1.0174x over previous
//
#include <hip/hip_runtime.h>

// Problem constants (from reference setup_inputs): B=8, L=4096, D=256, f32.
#define BATCH 8
#define SEQ   4096
#define DIM   256

// Native clang vector type — required by __builtin_nontemporal_store.
typedef float floatx4 __attribute__((ext_vector_type(4)));

// R10 model (fits all rounds with ~1.2x rocprof inflation): k1 is
// LATENCY-bound at ~1 outstanding load/wave — invariant to cache residency
// (R8 warm FETCH~0 still 48us), occupancy, and loop shape, because the
// compiler serializes VGPR-destination loads behind the recurrence chain.
// Fix: async global->LDS staging (__builtin_amdgcn_global_load_lds) —
// no dest VGPRs, drained only at the barrier, so a block keeps its whole
// 64KB tile in flight (128KB/CU at 2 blocks/CU).

// ---------------------------------------------------------------------------
// Kernel 1 (NT=256 path): one block per (b,tile). 4 waves stage the 4 arrays'
// 16KB tile chunks into LDS asynchronously; one barrier; each thread then
// scans its d-column from LDS (product chain + y-from-zero chain).
// ---------------------------------------------------------------------------
template <int NT, int T>
__global__ __launch_bounds__(256) void k_tile_agg_lds(
    const float* __restrict__ Ar, const float* __restrict__ Ai,
    const float* __restrict__ Xr, const float* __restrict__ Xi,
    float4* __restrict__ agg)
{
    constexpr int TILE_FLOATS = T * DIM;            // 4096 floats = 16 KB/array
    __shared__ float lds[4 * TILE_FLOATS];          // 64 KB total

    int tile = blockIdx.x;                          // in [0, BATCH*NT)
    int b = tile / NT;
    int j = tile - b * NT;

    int wave = threadIdx.x >> 6;                    // 0..3 -> which array
    int lane = threadIdx.x & 63;

    size_t tile_off = ((size_t)b * SEQ + (size_t)j * T) * DIM;   // float idx

    // Wave w streams array w: T issues of 1KB (64 lanes x 16B), LDS linear.
    const float* src = (wave == 0) ? Ar : (wave == 1) ? Ai
                      : (wave == 2) ? Xr : Xi;
    const float* gsrc = src + tile_off + (size_t)lane * 4;
    float* lbase = &lds[wave * TILE_FLOATS];

#pragma unroll
    for (int s = 0; s < T; ++s) {
        __builtin_amdgcn_global_load_lds(
            (const __attribute__((address_space(1))) void*)(gsrc + s * DIM),
            (__attribute__((address_space(3))) void*)(lbase + s * DIM),
            16, 0, 0);
    }
    __syncthreads();   // compiler emits s_waitcnt vmcnt(0) before s_barrier

    // Compute phase: thread owns one d-column. Stride-1 across lanes ->
    // 2 lanes/bank (free, m136).
    int d = threadIdx.x;
    float pr = 1.f, pi = 0.f, yr = 0.f, yi = 0.f;
#pragma unroll
    for (int t = 0; t < T; ++t) {
        float a_r = lds[0 * TILE_FLOATS + t * DIM + d];
        float a_i = lds[1 * TILE_FLOATS + t * DIM + d];
        float x_r = lds[2 * TILE_FLOATS + t * DIM + d];
        float x_i = lds[3 * TILE_FLOATS + t * DIM + d];
        float npr = a_r * pr - a_i * pi;
        float npi = a_r * pi + a_i * pr;
        pr = npr; pi = npi;
        float nyr = a_r * yr - a_i * yi + x_r;
        float nyi = a_r * yi + a_i * yr + x_i;
        yr = nyr; yi = nyi;
    }

    agg[((size_t)b * NT + j) * DIM + d] = make_float4(pr, pi, yr, yi);
}

// ---------------------------------------------------------------------------
// Kernel 1 fallback (small ws): R10 form, float4, 4 cols/lane, 1 wave/tile.
// ---------------------------------------------------------------------------
template <int NT, int T>
__global__ __launch_bounds__(256) void k_tile_agg(
    const float* __restrict__ Ar, const float* __restrict__ Ai,
    const float* __restrict__ Xr, const float* __restrict__ Xi,
    float4* __restrict__ agg)
{
    int wave = threadIdx.x >> 6;
    int lane = threadIdx.x & 63;
    int tile = blockIdx.x * 4 + wave;
    int b = tile / NT;
    int j = tile - b * NT;
    int d = lane * 4;

    size_t base = ((size_t)b * SEQ + (size_t)j * T) * DIM + d;

    float pr[4], pi[4], yr[4], yi[4];
#pragma unroll
    for (int k = 0; k < 4; ++k) { pr[k] = 1.f; pi[k] = 0.f; yr[k] = 0.f; yi[k] = 0.f; }

#pragma unroll 4
    for (int t = 0; t < T; ++t) {
        size_t idx = base + (size_t)t * DIM;
        float4 a_re = *(const float4*)(Ar + idx);
        float4 a_im = *(const float4*)(Ai + idx);
        float4 x_re = *(const float4*)(Xr + idx);
        float4 x_im = *(const float4*)(Xi + idx);
        const float* par = (const float*)&a_re;
        const float* pai = (const float*)&a_im;
        const float* pxr = (const float*)&x_re;
        const float* pxi = (const float*)&x_im;
#pragma unroll
        for (int k = 0; k < 4; ++k) {
            float a_r = par[k], a_i = pai[k];
            float npr = a_r * pr[k] - a_i * pi[k];
            float npi = a_r * pi[k] + a_i * pr[k];
            pr[k] = npr; pi[k] = npi;
            float nyr = a_r * yr[k] - a_i * yi[k] + pxr[k];
            float nyi = a_r * yi[k] + a_i * yr[k] + pxi[k];
            yr[k] = nyr; yi[k] = nyi;
        }
    }

    size_t o = ((size_t)b * NT + j) * DIM + d;
#pragma unroll
    for (int k = 0; k < 4; ++k)
        agg[o + k] = make_float4(pr[k], pi[k], yr[k], yi[k]);
}

// ---------------------------------------------------------------------------
// Kernel 2: wave-parallel exclusive scan of tile aggregates along j.
// One wave per (b,d) column; lane owns NTPL = NT/64 consecutive tiles.
// ---------------------------------------------------------------------------
template <int NT>
__global__ __launch_bounds__(256) void k_scan_agg(float4* __restrict__ agg)
{
    constexpr int NTPL = NT / 64;
    int lane = threadIdx.x & 63;
    int col  = blockIdx.x * 4 + (threadIdx.x >> 6);   // in [0, BATCH*DIM)
    int b = col >> 8;          // / DIM
    int d = col & 255;         // % DIM

    float4 v[NTPL];
    float lar = 1.f, lai = 0.f, lxr = 0.f, lxi = 0.f;
#pragma unroll
    for (int m = 0; m < NTPL; ++m) {
        v[m] = agg[((size_t)b * NT + lane * NTPL + m) * DIM + d];
        float nar = v[m].x * lar - v[m].y * lai;
        float nai = v[m].x * lai + v[m].y * lar;
        float nxr = v[m].x * lxr - v[m].y * lxi + v[m].z;
        float nxi = v[m].x * lxi + v[m].y * lxr + v[m].w;
        lar = nar; lai = nai; lxr = nxr; lxi = nxi;
    }

    float ar = lar, ai = lai, xr = lxr, xi = lxi;
#pragma unroll
    for (int off = 1; off < 64; off <<= 1) {
        float par = __shfl_up(ar, (unsigned)off, 64);
        float pai = __shfl_up(ai, (unsigned)off, 64);
        float pxr = __shfl_up(xr, (unsigned)off, 64);
        float pxi = __shfl_up(xi, (unsigned)off, 64);
        if (lane >= off) {
            float nar = ar * par - ai * pai;
            float nai = ar * pai + ai * par;
            float nxr = ar * pxr - ai * pxi + xr;
            float nxi = ar * pxi + ai * pxr + xi;
            ar = nar; ai = nai; xr = nxr; xi = nxi;
        }
    }

    float ear = __shfl_up(ar, 1u, 64);
    float eai = __shfl_up(ai, 1u, 64);
    float exr = __shfl_up(xr, 1u, 64);
    float exi = __shfl_up(xi, 1u, 64);
    if (lane == 0) { ear = 1.f; eai = 0.f; exr = 0.f; exi = 0.f; }

#pragma unroll
    for (int m = 0; m < NTPL; ++m) {
        agg[((size_t)b * NT + lane * NTPL + m) * DIM + d] =
            make_float4(exr, exi, 0.f, 0.f);
        float nar = v[m].x * ear - v[m].y * eai;
        float nai = v[m].x * eai + v[m].y * ear;
        float nxr = v[m].x * exr - v[m].y * exi + v[m].z;
        float nxi = v[m].x * exi + v[m].y * exr + v[m].w;
        ear = nar; eai = nai; exr = nxr; exi = nxi;
    }
}

// ---------------------------------------------------------------------------
// Kernel 3 (R8/R10 fast form, unchanged): seed y from tile prefix, recompute
// recurrence, write out. Tile = 2 waves; 2 cols/lane (float2 loads); one
// contiguous 16B nontemporal store per lane per t ([B,L,D,2] layout).
// ---------------------------------------------------------------------------
template <int NT, int T>
__global__ __launch_bounds__(256, 8) void k_apply(
    const float* __restrict__ Ar, const float* __restrict__ Ai,
    const float* __restrict__ Xr, const float* __restrict__ Xi,
    const float4* __restrict__ agg, float* __restrict__ outf)
{
    int half = threadIdx.x >> 7;
    int wl   = threadIdx.x & 127;
    int tile = blockIdx.x * 2 + half;
    int b = tile / NT;
    int j = tile - b * NT;
    int d = wl * 2;

    float yr[2], yi[2];
    size_t o = ((size_t)b * NT + j) * DIM + d;
    {
        float4 p0 = agg[o];
        float4 p1 = agg[o + 1];
        yr[0] = p0.x; yi[0] = p0.y;
        yr[1] = p1.x; yi[1] = p1.y;
    }

    size_t base = ((size_t)b * SEQ + (size_t)j * T) * DIM + d;

#pragma unroll
    for (int t = 0; t < T; ++t) {
        size_t idx = base + (size_t)t * DIM;
        float2 a_re = *(const float2*)(Ar + idx);
        float2 a_im = *(const float2*)(Ai + idx);
        float2 x_re = *(const float2*)(Xr + idx);
        float2 x_im = *(const float2*)(Xi + idx);
        const float* par = (const float*)&a_re;
        const float* pai = (const float*)&a_im;
        const float* pxr = (const float*)&x_re;
        const float* pxi = (const float*)&x_im;
#pragma unroll
        for (int k = 0; k < 2; ++k) {
            float nyr = par[k] * yr[k] - pai[k] * yi[k] + pxr[k];
            float nyi = par[k] * yi[k] + pai[k] * yr[k] + pxi[k];
            yr[k] = nyr; yi[k] = nyi;
        }
        floatx4 o1 = (floatx4){yr[0], yi[0], yr[1], yi[1]};
        __builtin_nontemporal_store(o1, (floatx4*)(outf + 2 * idx));
    }
}

extern "C" void kernel_launch(void* const* d_in, const int* in_sizes, int n_in,
                              void* d_out, int out_size, void* d_ws, size_t ws_size,
                              hipStream_t stream)
{
    const float* Ar = (const float*)d_in[0];
    const float* Ai = (const float*)d_in[1];
    const float* Xr = (const float*)d_in[2];
    const float* Xi = (const float*)d_in[3];
    float* outf = (float*)d_out;
    float4* agg = (float4*)d_ws;

    dim3 block(256);

    if (ws_size >= (size_t)BATCH * 256 * DIM * sizeof(float4)) {
        constexpr int NT = 256, T = SEQ / 256;   // T = 16
        dim3 grid1(BATCH * NT);                  // k1: one block per tile
        dim3 grid3((BATCH * NT) / 2);            // k3: 2 waves/tile
        k_tile_agg_lds<NT, T><<<grid1, block, 0, stream>>>(Ar, Ai, Xr, Xi, agg);
        k_scan_agg<NT><<<(BATCH * DIM) / 4, block, 0, stream>>>(agg);
        k_apply<NT, T><<<grid3, block, 0, stream>>>(Ar, Ai, Xr, Xi, agg, outf);
    } else {
        constexpr int NT = 64, T = SEQ / 64;     // T = 64
        dim3 grid1((BATCH * NT) / 4);
        dim3 grid3((BATCH * NT) / 2);
        k_tile_agg<NT, T><<<grid1, block, 0, stream>>>(Ar, Ai, Xr, Xi, agg);
        k_scan_agg<NT><<<(BATCH * DIM) / 4, block, 0, stream>>>(agg);
        k_apply<NT, T><<<grid3, block, 0, stream>>>(Ar, Ai, Xr, Xi, agg, outf);
    }
}